// Round 11
// baseline (386.198 us; speedup 1.0000x reference)
//
#include <hip/hip_runtime.h>
#include <math.h>

#define NODES   50000
#define HEADS   4
#define HID     64
#define FDIM    256   // HEADS*HID
#define IN_CH   16
#define NEG_SLOPE 0.2f

typedef unsigned short ushort_t;
typedef unsigned int uint_t;
typedef __attribute__((ext_vector_type(8))) short bf16x8;
typedef __attribute__((ext_vector_type(4))) float f32x4;
typedef __attribute__((ext_vector_type(2))) float f32x2;

__device__ inline ushort_t f2bf(float f) {           // RNE fp32 -> bf16
    uint_t u = __float_as_uint(f);
    u += 0x7fffu + ((u >> 16) & 1u);
    return (ushort_t)(u >> 16);
}
__device__ inline uint_t f2h(float f) {              // fp32 -> fp16 bits (RTE)
    _Float16 h = (_Float16)f;
    return (uint_t)*(ushort_t*)&h;
}
__device__ inline float h2f(uint_t u) {              // fp16 bits -> fp32
    ushort_t us = (ushort_t)u;
    _Float16 h = *(_Float16*)&us;
    return (float)h;
}

// ---------------- merged: layer-1 GEMM + alpha1 (8 nodes/block) | W2T | hist ----------------

__global__ __launch_bounds__(256) void k_prep(const float* __restrict__ x,
                                              const float* __restrict__ W1,
                                              const float* __restrict__ as1,
                                              const float* __restrict__ ad1,
                                              const float* __restrict__ W2,
                                              const int* __restrict__ ei, int E,
                                              ushort_t* __restrict__ h,
                                              float* __restrict__ asrc,
                                              float* __restrict__ adst,
                                              ushort_t* __restrict__ W2T,
                                              int* __restrict__ deg, int Nn, int NB) {
    int bid = blockIdx.x, t = threadIdx.x;
    if (bid >= NB + 256) {                 // histogram tail
        int e = (bid - NB - 256) * 256 + t;
        int Etot = E + Nn;
        if (e >= Etot) return;
        int d = (e < E) ? ei[E + e] : (e - E);
        if (d >= 0 && d < Nn) atomicAdd(&deg[d], 1);
        return;
    }
    if (bid >= NB) {                       // W2T: 256 blocks, 65536 elements
        int idx = (bid - NB) * 256 + t;
        int n = idx >> 8, k = idx & 255;
        W2T[idx] = f2bf(W2[k * FDIM + n]);
        return;
    }
    float w1c[16];
#pragma unroll
    for (int k = 0; k < 16; ++k) w1c[k] = W1[k * FDIM + t];
    float av = as1[t], dv = ad1[t];       // as1/ad1 are [H][64] flat == [t]
    int hh = t >> 6;
#pragma unroll
    for (int j = 0; j < 8; ++j) {
        int n = bid * 8 + j;
        if (n >= Nn) break;
        const float4* xp = (const float4*)(x + n * IN_CH);
        float4 x0 = xp[0], x1 = xp[1], x2 = xp[2], x3 = xp[3];
        float s = x0.x * w1c[0]  + x0.y * w1c[1]  + x0.z * w1c[2]  + x0.w * w1c[3]
                + x1.x * w1c[4]  + x1.y * w1c[5]  + x1.z * w1c[6]  + x1.w * w1c[7]
                + x2.x * w1c[8]  + x2.y * w1c[9]  + x2.z * w1c[10] + x2.w * w1c[11]
                + x3.x * w1c[12] + x3.y * w1c[13] + x3.z * w1c[14] + x3.w * w1c[15];
        uint_t pv = (uint_t)f2bf(s);
        uint_t ov = __shfl_down(pv, 1);
        if (!(t & 1)) *(uint_t*)(h + (long)n * FDIM + t) = pv | (ov << 16);
        float p1 = s * av, p2 = s * dv;
#pragma unroll
        for (int off = 1; off < 64; off <<= 1) {
            p1 += __shfl_xor(p1, off);
            p2 += __shfl_xor(p2, off);
        }
        if ((t & 63) == 0) {
            asrc[n * 4 + hh] = p1;
            adst[n * 4 + hh] = p2;
        }
    }
}

// ---------------- parallel exclusive scan (B fused into C) ----------------

__global__ __launch_bounds__(256) void k_scanA(const int* __restrict__ deg,
                                               int* __restrict__ bsum, int N) {
    __shared__ int sh[256];
    int t = threadIdx.x;
    int i0 = blockIdx.x * 4096 + t * 16;
    int s = 0;
#pragma unroll
    for (int j = 0; j < 16; ++j) s += (i0 + j < N) ? deg[i0 + j] : 0;
    sh[t] = s;
    __syncthreads();
    for (int off = 128; off; off >>= 1) {
        if (t < off) sh[t] += sh[t + off];
        __syncthreads();
    }
    if (t == 0) bsum[blockIdx.x] = sh[0];
}

__global__ __launch_bounds__(256) void k_scanC(const int* __restrict__ deg,
                                               const int* __restrict__ bsum,
                                               int* __restrict__ rowst,
                                               int* __restrict__ cursor, int N, int nb) {
    __shared__ int sh[256];
    __shared__ int boff[64];
    int t = threadIdx.x, b = blockIdx.x;
    if (t < 64) {                        // wave 0: redundant 64-wide scan of bsum
        int orig = (t < nb) ? bsum[t] : 0;
        int v = orig;
#pragma unroll
        for (int off = 1; off < 64; off <<= 1) {
            int u = __shfl_up(v, off);
            if (t >= off) v += u;
        }
        boff[t] = v - orig;              // exclusive
        if (t == 63 && b == 0) rowst[N] = v;
    }
    int i0 = b * 4096 + t * 16;
    int v[16], s = 0;
#pragma unroll
    for (int j = 0; j < 16; ++j) { v[j] = (i0 + j < N) ? deg[i0 + j] : 0; s += v[j]; }
    sh[t] = s;
    __syncthreads();
    for (int off = 1; off < 256; off <<= 1) {
        int u = (t >= off) ? sh[t - off] : 0;
        __syncthreads();
        sh[t] += u;
        __syncthreads();
    }
    int excl = sh[t] - s + boff[b];
#pragma unroll
    for (int j = 0; j < 16; ++j) {
        if (i0 + j < N) { rowst[i0 + j] = excl; cursor[i0 + j] = excl; }
        excl += v[j];
    }
}

__global__ void k_scatter(const int* __restrict__ ei, int E, int N,
                          int* __restrict__ cursor, int2* __restrict__ csr2) {
    int e = blockIdx.x * blockDim.x + threadIdx.x;
    int Etot = E + N;
    if (e >= Etot) return;
    int s, d;
    if (e < E) { s = ei[e]; d = ei[E + e]; } else { s = d = e - E; }
    if (d < 0 || d >= N) return;
    int pos = atomicAdd(&cursor[d], 1);
    csr2[pos] = make_int2(s, d);
}

// ---------------- layer-2 GEMM (row-strip MFMA) + fused alpha2 ----------------
// grid = ceil(M/64) blocks; block stages A(64xk32) + ALL BT cols (256xk32) in LDS.
// wave = head: computes 64x64 tile via 4x4 MFMA frags; alpha2 by per-wave shuffle.

__global__ __launch_bounds__(256) void k_gemm2(const ushort_t* __restrict__ A,
                                               const ushort_t* __restrict__ BT,
                                               const float* __restrict__ as2,
                                               const float* __restrict__ ad2,
                                               ushort_t* __restrict__ C,
                                               float* __restrict__ asrc,
                                               float* __restrict__ adst, int M) {
    __shared__ short As[64 * 40];
    __shared__ short Bs[256 * 40];
    int tid = threadIdx.x;
    int row0 = blockIdx.x * 64;
    int w = tid >> 6, lane = tid & 63;    // wave == head == column strip
    int quad = lane >> 4, lm = lane & 15;
    int lr = tid >> 2, lk = (tid & 3) * 8;
    f32x4 acc[4][4] = {};
    for (int k0 = 0; k0 < FDIM; k0 += 32) {
        uint4 av = {0u, 0u, 0u, 0u};
        int ar = row0 + lr;
        if (ar < M) av = *(const uint4*)(A + (long)ar * FDIM + k0 + lk);
        *(uint4*)(&As[lr * 40 + lk]) = av;
#pragma unroll
        for (int seg = 0; seg < 4; ++seg) {
            int n = seg * 64 + lr;
            uint4 bv = *(const uint4*)(BT + (long)n * FDIM + k0 + lk);
            *(uint4*)(&Bs[n * 40 + lk]) = bv;
        }
        __syncthreads();
        bf16x8 af[4], bf[4];
#pragma unroll
        for (int i = 0; i < 4; ++i) {
            af[i] = *(const bf16x8*)(&As[(i * 16 + lm) * 40 + quad * 8]);
            bf[i] = *(const bf16x8*)(&Bs[(w * 64 + i * 16 + lm) * 40 + quad * 8]);
        }
#pragma unroll
        for (int mi = 0; mi < 4; ++mi)
#pragma unroll
            for (int ni = 0; ni < 4; ++ni)
                acc[mi][ni] = __builtin_amdgcn_mfma_f32_16x16x32_bf16(af[mi], bf[ni],
                                                                      acc[mi][ni], 0, 0, 0);
        __syncthreads();
    }
    // C store (bf16) — col = w*64 + ni*16 + lm, row = row0 + mi*16 + quad*4 + r
#pragma unroll
    for (int mi = 0; mi < 4; ++mi)
#pragma unroll
        for (int ni = 0; ni < 4; ++ni)
#pragma unroll
            for (int r = 0; r < 4; ++r) {
                int row = row0 + mi * 16 + quad * 4 + r;
                if (row < M)
                    C[(long)row * FDIM + w * 64 + ni * 16 + lm] = f2bf(acc[mi][ni][r]);
            }
    // fused alpha2: per-row dots vs as2/ad2 of this wave's head
    float asv[4], adv[4];
#pragma unroll
    for (int ni = 0; ni < 4; ++ni) {
        asv[ni] = as2[w * 64 + ni * 16 + lm];
        adv[ni] = ad2[w * 64 + ni * 16 + lm];
    }
#pragma unroll
    for (int mi = 0; mi < 4; ++mi)
#pragma unroll
        for (int r = 0; r < 4; ++r) {
            float ps = acc[mi][0][r] * asv[0] + acc[mi][1][r] * asv[1]
                     + acc[mi][2][r] * asv[2] + acc[mi][3][r] * asv[3];
            float pd = acc[mi][0][r] * adv[0] + acc[mi][1][r] * adv[1]
                     + acc[mi][2][r] * adv[2] + acc[mi][3][r] * adv[3];
#pragma unroll
            for (int off = 1; off < 16; off <<= 1) {
                ps += __shfl_xor(ps, off);
                pd += __shfl_xor(pd, off);
            }
            if (lm == 0) {
                int row = row0 + mi * 16 + quad * 4 + r;
                if (row < M) {
                    asrc[row * 4 + w] = ps;
                    adst[row * 4 + w] = pd;
                }
            }
        }
}

// ---------------- edge-parallel pw precompute: u32 = (src<<16) | fp16(pw) ----------------

__global__ void k_pw(const int2* __restrict__ csr2, const float* __restrict__ asrc,
                     const float* __restrict__ adst, uint_t* __restrict__ pwb, int Etot) {
    int e = blockIdx.x * blockDim.x + threadIdx.x;
    if (e >= Etot) return;
    int2 sd = csr2[e];
    float4 av = *(const float4*)(asrc + sd.x * 4);
    float4 dv = *(const float4*)(adst + sd.y * 4);
    float t[4] = {av.x + dv.x, av.y + dv.y, av.z + dv.z, av.w + dv.w};
    uint_t sh = (uint_t)sd.x << 16;
#pragma unroll
    for (int h = 0; h < 4; ++h) {
        float tt = (t[h] > 0.f) ? t[h] : NEG_SLOPE * t[h];
        pwb[h * Etot + e] = sh | f2h(__expf(tt));
    }
}

// ---------------- segment-softmax aggregate (pwb, 4x in flight, fused epilogues) ----------------

__device__ inline void fma8(f32x2& a0, f32x2& a1, f32x2& a2, f32x2& a3,
                            uint4 hv, float pw) {
    f32x2 p = {pw, pw};
    f32x2 u;
    u.x = __uint_as_float(hv.x << 16); u.y = __uint_as_float(hv.x & 0xffff0000u);
    a0 += p * u;
    u.x = __uint_as_float(hv.y << 16); u.y = __uint_as_float(hv.y & 0xffff0000u);
    a1 += p * u;
    u.x = __uint_as_float(hv.z << 16); u.y = __uint_as_float(hv.z & 0xffff0000u);
    a2 += p * u;
    u.x = __uint_as_float(hv.w << 16); u.y = __uint_as_float(hv.w & 0xffff0000u);
    a3 += p * u;
}

__global__ __launch_bounds__(256) void k_agg(const ushort_t* __restrict__ h,
                                             const uint_t* __restrict__ pwb,
                                             const int* __restrict__ row_start,
                                             const float* __restrict__ b1,
                                             const float* __restrict__ b2,
                                             const float* __restrict__ Wc,
                                             const float* __restrict__ bc,
                                             ushort_t* __restrict__ hout,
                                             float* __restrict__ fout,
                                             int mode, int Etot, int N) {
    __shared__ float zsh[2 * FDIM];    // 2 nodes x 256 ch (head-major)
    __shared__ float wsh[584];         // Wc(512) | bc(8) | b2(64)
    int tid  = threadIdx.x;
    int hh   = tid >> 6;
    int lane = tid & 63;
    int half = lane >> 5;
    int l32  = lane & 31;
    int g    = l32 >> 3;       // edge subgroup 0..3
    int cg   = l32 & 7;        // channel oct 0..7
    int d    = blockIdx.x * 2 + half;
    bool valid = d < N;

    if (!mode) {
        for (int i = tid; i < 584; i += 256)
            wsh[i] = (i < 512) ? Wc[i] : ((i < 520) ? bc[i - 512] : b2[i - 520]);
    }

    int s0 = 0, s1 = 0;
    if (valid) { s0 = row_start[d]; s1 = row_start[d + 1]; }
    int cnt  = s1 - s0;
    int maxc = max(cnt, __shfl_xor(cnt, 32));
    const uint_t* pwp = pwb + (long)hh * Etot;
    const char* hbase = (const char*)h + (hh * HID + cg * 8) * 2;

    f32x2 a0 = {0.f, 0.f}, a1 = {0.f, 0.f}, a2 = {0.f, 0.f}, a3 = {0.f, 0.f};
    float den = 0.f;

    for (int off = 0; off < maxc; off += 16) {
        int i0 = s0 + off + g;
        uint_t u0 = (i0      < s1) ? pwp[i0]      : 0u;
        uint_t u1 = (i0 + 4  < s1) ? pwp[i0 + 4]  : 0u;
        uint_t u2 = (i0 + 8  < s1) ? pwp[i0 + 8]  : 0u;
        uint_t u3 = (i0 + 12 < s1) ? pwp[i0 + 12] : 0u;
        uint4 hv0 = *(const uint4*)(hbase + ((size_t)(u0 >> 16) << 9));
        uint4 hv1 = *(const uint4*)(hbase + ((size_t)(u1 >> 16) << 9));
        uint4 hv2 = *(const uint4*)(hbase + ((size_t)(u2 >> 16) << 9));
        uint4 hv3 = *(const uint4*)(hbase + ((size_t)(u3 >> 16) << 9));
        float pw0 = h2f(u0 & 0xffffu), pw1 = h2f(u1 & 0xffffu);
        float pw2 = h2f(u2 & 0xffffu), pw3 = h2f(u3 & 0xffffu);
        den += (pw0 + pw1) + (pw2 + pw3);
        fma8(a0, a1, a2, a3, hv0, pw0);
        fma8(a0, a1, a2, a3, hv1, pw1);
        fma8(a0, a1, a2, a3, hv2, pw2);
        fma8(a0, a1, a2, a3, hv3, pw3);
    }
#pragma unroll
    for (int off = 8; off <= 16; off <<= 1) {
        a0.x += __shfl_xor(a0.x, off); a0.y += __shfl_xor(a0.y, off);
        a1.x += __shfl_xor(a1.x, off); a1.y += __shfl_xor(a1.y, off);
        a2.x += __shfl_xor(a2.x, off); a2.y += __shfl_xor(a2.y, off);
        a3.x += __shfl_xor(a3.x, off); a3.y += __shfl_xor(a3.y, off);
        den  += __shfl_xor(den, off);
    }

    if (mode) {
        if (g == 0 && valid) {
            float inv = 1.f / den;
            float v[8] = {a0.x, a0.y, a1.x, a1.y, a2.x, a2.y, a3.x, a3.y};
            const float* bp = b1 + hh * HID + cg * 8;
#pragma unroll
            for (int j = 0; j < 8; ++j) {
                float t = v[j] * inv + bp[j];
                v[j] = (t > 0.f) ? t : __expf(t) - 1.f;
            }
            uint4 u;
            u.x = (uint_t)f2bf(v[0]) | ((uint_t)f2bf(v[1]) << 16);
            u.y = (uint_t)f2bf(v[2]) | ((uint_t)f2bf(v[3]) << 16);
            u.z = (uint_t)f2bf(v[4]) | ((uint_t)f2bf(v[5]) << 16);
            u.w = (uint_t)f2bf(v[6]) | ((uint_t)f2bf(v[7]) << 16);
            *(uint4*)(hout + (long)d * FDIM + hh * HID + cg * 8) = u;
        }
    } else {
        if (g == 0 && valid) {
            float inv = 1.f / den;
            float v[8] = {a0.x, a0.y, a1.x, a1.y, a2.x, a2.y, a3.x, a3.y};
            int zb = half * FDIM + hh * HID + cg * 8;
#pragma unroll
            for (int j = 0; j < 8; ++j) zsh[zb + j] = v[j] * inv;
        }
        __syncthreads();
        if (tid < 128) {                 // head-mean + b2 + ELU
            int node = tid >> 6, c = tid & 63;
            int dd = blockIdx.x * 2 + node;
            if (dd < N) {
                const float* zp = zsh + node * FDIM;
                float zv = 0.25f * (zp[c] + zp[64 + c] + zp[128 + c] + zp[192 + c])
                         + wsh[520 + c];
                zv = (zv > 0.f) ? zv : __expf(zv) - 1.f;
                zsh[node * FDIM + c] = zv;
            }
        }
        __syncthreads();
        if (tid < 16) {                  // GEMV [64x8] + bc
            int node = tid >> 3, o = tid & 7;
            int dd = blockIdx.x * 2 + node;
            if (dd < N) {
                float acc = wsh[512 + o];
                const float* zp = zsh + node * FDIM;
#pragma unroll 8
                for (int c = 0; c < 64; ++c) acc += zp[c] * wsh[c * 8 + o];
                fout[(long)dd * 8 + o] = acc;
            }
        }
    }
}

// ---------------- launch ----------------

extern "C" void kernel_launch(void* const* d_in, const int* in_sizes, int n_in,
                              void* d_out, int out_size, void* d_ws, size_t ws_size,
                              hipStream_t stream) {
    const float* x   = (const float*)d_in[0];
    const int*   ei  = (const int*)d_in[1];
    const float* W1  = (const float*)d_in[2];
    const float* as1 = (const float*)d_in[3];
    const float* ad1 = (const float*)d_in[4];
    const float* b1  = (const float*)d_in[5];
    const float* W2  = (const float*)d_in[6];
    const float* as2 = (const float*)d_in[7];
    const float* ad2 = (const float*)d_in[8];
    const float* b2  = (const float*)d_in[9];
    const float* Wc  = (const float*)d_in[10];
    const float* bc  = (const float*)d_in[11];
    float* out = (float*)d_out;

    const int N = NODES;
    const int E = in_sizes[1] / 2;
    const int Etot = E + N;

    char* ws = (char*)d_ws;
    size_t off = 0;
    auto alloc = [&](size_t bytes) {
        void* p = ws + off;
        off = (off + bytes + 255) & ~(size_t)255;
        return p;
    };
    ushort_t* hbf    = (ushort_t*)alloc((size_t)N * FDIM * 2);   // h (bf16), both layers
    ushort_t* hact   = (ushort_t*)alloc((size_t)N * FDIM * 2);   // act1 (bf16)
    float*    asrc   = (float*)alloc((size_t)N * HEADS * 4);
    float*    adst   = (float*)alloc((size_t)N * HEADS * 4);
    ushort_t* W2T    = (ushort_t*)alloc((size_t)FDIM * FDIM * 2);
    int*      deg    = (int*)alloc((size_t)N * 4);
    int*      rowst  = (int*)alloc((size_t)(N + 1) * 4);
    int*      cursor = (int*)alloc((size_t)N * 4);
    int*      bsum   = (int*)alloc(64 * 4);
    int2*     csr2   = (int2*)alloc((size_t)Etot * 8);
    uint_t*   pwb    = (uint_t*)alloc((size_t)Etot * HEADS * 4);

    const int tpb = 256;
    int egrid = (Etot + tpb - 1) / tpb;
    int nb = (N + 4095) / 4096;
    int NB = (N + 7) / 8;

    hipMemsetAsync(deg, 0, (size_t)N * 4, stream);

    // Merged: layer-1 gemm+alpha | W2T | histogram
    k_prep<<<NB + 256 + egrid, tpb, 0, stream>>>(x, W1, as1, ad1, W2, ei, E,
                                                 hbf, asrc, adst, W2T, deg, N, NB);
    k_scanA<<<nb, 256, 0, stream>>>(deg, bsum, N);
    k_scanC<<<nb, 256, 0, stream>>>(deg, bsum, rowst, cursor, N, nb);
    k_scatter<<<egrid, tpb, 0, stream>>>(ei, E, N, cursor, csr2);

    // Layer 1 aggregate (+b1, ELU)
    k_pw<<<egrid, tpb, 0, stream>>>(csr2, asrc, adst, pwb, Etot);
    k_agg<<<(N + 1) / 2, 256, 0, stream>>>(hbf, pwb, rowst, b1, nullptr, nullptr, nullptr,
                                           hact, nullptr, 1, Etot, N);

    // Layer 2 (row-strip gemm + fused alpha2)
    k_gemm2<<<(N + 63) / 64, 256, 0, stream>>>(hact, W2T, as2, ad2, hbf, asrc, adst, N);
    k_pw<<<egrid, tpb, 0, stream>>>(csr2, asrc, adst, pwb, Etot);
    k_agg<<<(N + 1) / 2, 256, 0, stream>>>(hbf, pwb, rowst, nullptr, b2, Wc, bc,
                                           nullptr, out, 0, Etot, N);
}